// Round 7
// baseline (332.606 us; speedup 1.0000x reference)
//
#include <hip/hip_runtime.h>
#include <hip/hip_bf16.h>

// Problem constants
#define B_N 16384
#define A_N 32
#define U_N 64
#define S_N 2048
#define E_N 32
#define HYP_N 64
#define H_N 4
#define NREAL 288   // 256 selector-hypernet cols + 32 v-net cols
#define NPADG 320   // GEMM N padded to 320 (20 MFMA col-tiles)

// workspace byte offsets (16B-aligned)
#define WS_WT    0                         // Wt bf16 [320][2048] = 1310720 B
#define WS_MB    1310720                   // Mb bf16 [H][U][64]  = 32768 B
#define WS_PMAG  (WS_MB + 32768)
#define WS_PENT  (WS_PMAG + 65536)

// output layout (floats): head_attend [B,A] | v [B] | mag | ent [H]
#define OUT_V   (B_N * A_N)
#define OUT_MAG (OUT_V + B_N)
#define OUT_ENT (OUT_MAG + 1)

typedef __attribute__((ext_vector_type(8))) short bf16x8_t;
typedef __attribute__((ext_vector_type(4))) float floatx4_t;

__device__ __forceinline__ unsigned short f2b(float f) {
    union { float f; unsigned u; } v; v.f = f;
    unsigned r = v.u + 0x7FFFu + ((v.u >> 16) & 1u);   // RNE
    return (unsigned short)(r >> 16);
}
__device__ __forceinline__ float b2f(unsigned x) {
    union { unsigned u; float f; } v; v.u = x << 16; return v.f;
}

// ---------------------------------------------------------------------------
// Pack: Wt bf16 [320][2048] (W^T of [sel_w1 | v_w1 | 0]) and
//       Mb bf16 [H][U][64]: M[h][u][k] = sum_e key_w[h][u][e]*sel_w2[h][k][e]
// ---------------------------------------------------------------------------
__global__ __launch_bounds__(256) void pack_w_kernel(
        const float* __restrict__ sel_w1, const float* __restrict__ v_w1,
        const float* __restrict__ sel_w2, const float* __restrict__ key_w,
        unsigned short* __restrict__ Wt, unsigned short* __restrict__ Mb) {
    int idx = blockIdx.x * 256 + threadIdx.x;
    if (idx < NPADG * S_N) {
        int n = idx >> 11;          // / 2048
        int k = idx & 2047;
        float val = 0.0f;
        if (n < 256) {
            int h = n >> 6, kk = n & 63;
            val = sel_w1[((size_t)h * S_N + k) * HYP_N + kk];
        } else if (n < NREAL) {
            val = v_w1[(size_t)k * E_N + (n - 256)];
        }
        Wt[idx] = f2b(val);
    } else if (idx < NPADG * S_N + H_N * U_N * HYP_N) {
        int j = idx - NPADG * S_N;          // [h][u][k]
        int h = j >> 12, u = (j >> 6) & 63, k = j & 63;
        const float* kw = key_w + ((size_t)h * U_N + u) * E_N;
        const float* w2 = sel_w2 + ((size_t)h * HYP_N + k) * E_N;
        float s = 0.0f;
#pragma unroll
        for (int e = 0; e < E_N; ++e) s = fmaf(kw[e], w2[e], s);
        Mb[j] = f2b(s);
    }
}

// ---------------------------------------------------------------------------
// Fused kernel v3: barrier-free K-loop.
//   A (the HBM stream): chunked into 8 x K=256, fp32 -> regs one chunk ahead,
//     cvt bf16 -> double-buffered LDS. ONE barrier per chunk (8 total).
//   B (1.3 MB, L2-resident): loaded per k-step DIRECTLY into MFMA-layout
//     registers (rolling 2-deep queue). No LDS, no barriers.
//   Then bias/relu -> h1 LDS, phase T (MFMA t = h1 @ M^T), phase L (softmax).
// 256 thr (4 waves, N-split 80 cols each), grid 512 -> 2 blocks/CU.
// A-LDS swizzle: phys octet = (o&24)|((o&7)^(r&7)) -> <=2-way banks.
// ---------------------------------------------------------------------------
#define FM_BM 32
#define CHK 256                  // K per chunk
#define NCHK (S_N / CHK)         // 8
#define KSC (CHK / 32)           // 8 k-steps per chunk
#define H1_STRIDE 312   // shorts
#define TS_STRIDE 260   // floats

__global__ __launch_bounds__(256, 2) void fused_kernel(
        const float* __restrict__ states, const unsigned short* __restrict__ Wt,
        const float* __restrict__ sel_b1, const float* __restrict__ v_b1,
        const unsigned short* __restrict__ Mb,
        const float* __restrict__ v_w2, const float* __restrict__ v_b2,
        float* __restrict__ out, float* __restrict__ pmag, float* __restrict__ pent) {
    // pool: Abuf 2x16384 B (K-loop) ; phases alias: h1b 19968 B + tsb 33280 B
    __shared__ __align__(16) char pool[53248];
    unsigned short* Abuf = (unsigned short*)pool;       // 2 x 8192 shorts
    unsigned short* h1b  = (unsigned short*)pool;       // [32][312]
    float*          tsb  = (float*)(pool + 19968);      // [32][260]

    const int t = threadIdx.x;
    const int lane = t & 63;
    const int w = t >> 6;               // 0..3
    const int m0 = blockIdx.x * FM_BM;
    const int nw = w * 80;              // 4-way N split: 5 tiles/wave

    // A staging: thread t owns row ar = t>>3, k-quadoctet aq = t&7 (32 floats)
    const int ar = t >> 3, aq = t & 7;
    const float* abase = states + (size_t)(m0 + ar) * S_N + aq * 32;

    floatx4_t acc[2][5] = {};
    float4 avn[8];
    bf16x8_t bq[2][5];
    const int bn15 = lane & 15, bko = (lane >> 4) * 8;

    auto loadA = [&](int ch) {
        const float* g = abase + ch * CHK;
#pragma unroll
        for (int i = 0; i < 8; ++i) avn[i] = ((const float4*)g)[i];
    };
    auto writeA = [&](unsigned short* dst) {
#pragma unroll
        for (int j = 0; j < 4; ++j) {
            int o = aq * 4 + j;
            int ph = (o & 24) | ((o & 7) ^ (ar & 7));
            uint4 u;
            u.x = (unsigned)f2b(avn[2*j].x)   | ((unsigned)f2b(avn[2*j].y)   << 16);
            u.y = (unsigned)f2b(avn[2*j].z)   | ((unsigned)f2b(avn[2*j].w)   << 16);
            u.z = (unsigned)f2b(avn[2*j+1].x) | ((unsigned)f2b(avn[2*j+1].y) << 16);
            u.w = (unsigned)f2b(avn[2*j+1].z) | ((unsigned)f2b(avn[2*j+1].w) << 16);
            *(uint4*)(dst + ar * 256 + ph * 8) = u;
        }
    };
    auto loadB = [&](bf16x8_t* q, int ksg) {
#pragma unroll
        for (int nt = 0; nt < 5; ++nt) {
            int n = nw + nt * 16 + bn15;
            q[nt] = *(const bf16x8_t*)(Wt + (size_t)n * S_N + ksg * 32 + bko);
        }
    };

    // ---- prologue: chunk0 -> LDS buf0; chunk1 -> regs; B queue primed ----
    loadA(0);
    writeA(Abuf);
    loadA(1);
    loadB(bq[0], 0);
    loadB(bq[1], 1);
    __syncthreads();

    // ---- K-loop: 8 chunks, ONE barrier each; inner 8 k-steps barrier-free --
#pragma unroll 1
    for (int chunk = 0; chunk < NCHK; ++chunk) {
        unsigned short* As = Abuf + (chunk & 1) * 8192;
        if (chunk < NCHK - 1) {
            writeA(Abuf + ((chunk & 1) ^ 1) * 8192);   // avn = chunk+1
            if (chunk < NCHK - 2) loadA(chunk + 2);    // deep HBM prefetch
        }
#pragma unroll
        for (int ks = 0; ks < KSC; ++ks) {
            bf16x8_t af[2];
#pragma unroll
            for (int mt = 0; mt < 2; ++mt) {
                int r = mt * 16 + (lane & 15);
                int o = ks * 4 + (lane >> 4);
                int ph = (o & 24) | ((o & 7) ^ (r & 7));
                af[mt] = *(const bf16x8_t*)(As + r * 256 + ph * 8);
            }
#pragma unroll
            for (int nt = 0; nt < 5; ++nt) {
                acc[0][nt] = __builtin_amdgcn_mfma_f32_16x16x32_bf16(
                    af[0], bq[ks & 1][nt], acc[0][nt], 0, 0, 0);
                acc[1][nt] = __builtin_amdgcn_mfma_f32_16x16x32_bf16(
                    af[1], bq[ks & 1][nt], acc[1][nt], 0, 0, 0);
            }
            if (ks < KSC - 2 || chunk < NCHK - 1)
                loadB(bq[ks & 1], chunk * KSC + ks + 2);
        }
        __syncthreads();   // chunk readers done; next buffer's writes visible
    }

    // ---- bias + relu -> h1 LDS (bf16). C/D: col=lane&15, row=(lane>>4)*4+rg
    // layout per row: head h at h*72 (k 0..63), v-col j at (j>>3)*72+64+(j&7)
#pragma unroll
    for (int nt = 0; nt < 5; ++nt) {
        int n = nw + nt * 16 + (lane & 15);
        if (n >= NREAL) continue;
        float bias = (n < 256) ? sel_b1[n] : v_b1[n - 256];
        int slot = (n < 256) ? ((n >> 6) * 72 + (n & 63))
                             : (((n - 256) >> 3) * 72 + 64 + ((n - 256) & 7));
#pragma unroll
        for (int mt = 0; mt < 2; ++mt) {
#pragma unroll
            for (int rg = 0; rg < 4; ++rg) {
                int r = mt * 16 + (lane >> 4) * 4 + rg;
                float v = acc[mt][nt][rg] + bias;
                h1b[r * H1_STRIDE + slot] = f2b(v > 0.0f ? v : 0.0f);
            }
        }
    }
    __syncthreads();

    // ---- phase T: wave w = head h; t[r][h][u] via MFMA ----
    {
        const int h = w;
        floatx4_t tacc[2][4] = {};
#pragma unroll
        for (int s = 0; s < 2; ++s) {
            int k0 = s * 32 + (lane >> 4) * 8;
            bf16x8_t bfr[4];
#pragma unroll
            for (int ut = 0; ut < 4; ++ut) {
                int u = ut * 16 + (lane & 15);
                bfr[ut] = *(const bf16x8_t*)(Mb + ((size_t)(h * U_N + u) * 64) + k0);
            }
#pragma unroll
            for (int mt = 0; mt < 2; ++mt) {
                int r = mt * 16 + (lane & 15);
                bf16x8_t afr = *(const bf16x8_t*)(h1b + r * H1_STRIDE + h * 72 + k0);
#pragma unroll
                for (int ut = 0; ut < 4; ++ut)
                    tacc[mt][ut] = __builtin_amdgcn_mfma_f32_16x16x32_bf16(
                        afr, bfr[ut], tacc[mt][ut], 0, 0, 0);
            }
        }
#pragma unroll
        for (int mt = 0; mt < 2; ++mt)
#pragma unroll
            for (int ut = 0; ut < 4; ++ut)
#pragma unroll
                for (int rg = 0; rg < 4; ++rg) {
                    int r = mt * 16 + (lane >> 4) * 4 + rg;
                    int u = ut * 16 + (lane & 15);
                    tsb[r * TS_STRIDE + h * U_N + u] = tacc[mt][ut][rg];
                }
    }
    __syncthreads();

    // ---- phase L: wave w handles rows w*8 .. w*8+7 ----
    const int a = lane & 31, uh = lane >> 5;
    float4 cur[8], nxt[8];
    {
        const float* up = states + (size_t)(m0 + w * 8) * S_N + a * 64 + uh * 32;
#pragma unroll
        for (int i = 0; i < 8; ++i) cur[i] = ((const float4*)up)[i];
    }
    for (int rr = 0; rr < 8; ++rr) {
        int r = w * 8 + rr;
        int b = m0 + r;
        if (rr < 7) {
            const float* up = states + (size_t)(b + 1) * S_N + a * 64 + uh * 32;
#pragma unroll
            for (int i = 0; i < 8; ++i) nxt[i] = ((const float4*)up)[i];
        }
        float pl[4];
#pragma unroll
        for (int h = 0; h < 4; ++h) {
            const float* tp = &tsb[r * TS_STRIDE + h * U_N + uh * 32];
            float s = 0.0f;
#pragma unroll
            for (int i = 0; i < 8; ++i) {
                float4 t4 = *(const float4*)(tp + i * 4);
                s = fmaf(cur[i].x, t4.x, s);
                s = fmaf(cur[i].y, t4.y, s);
                s = fmaf(cur[i].z, t4.z, s);
                s = fmaf(cur[i].w, t4.w, s);
            }
            pl[h] = s + __shfl_xor(s, 32, 64);   // combine u-halves
        }
        float mg = pl[0]*pl[0] + pl[1]*pl[1] + pl[2]*pl[2] + pl[3]*pl[3];
#pragma unroll
        for (int o = 16; o > 0; o >>= 1) mg += __shfl_xor(mg, o, 32);
        float hatt = 0.0f;
        float entv[4];
#pragma unroll
        for (int h = 0; h < 4; ++h) {
            float x = pl[h] * 0.17677669529663687f;   // 1/sqrt(E=32)
            float m = x;
#pragma unroll
            for (int o = 16; o > 0; o >>= 1) m = fmaxf(m, __shfl_xor(m, o, 32));
            float p = expf(x - m);
            float den = p;
#pragma unroll
            for (int o = 16; o > 0; o >>= 1) den += __shfl_xor(den, o, 32);
            float wv = p / den;
            hatt += wv;
            float e = wv * logf(wv + 1e-8f);
#pragma unroll
            for (int o = 16; o > 0; o >>= 1) e += __shfl_xor(e, o, 32);
            entv[h] = e;
        }
        if (uh == 0) {
            out[(size_t)b * A_N + a] = hatt;
            float pv = b2f((unsigned)h1b[r * H1_STRIDE + (a >> 3) * 72 + 64 + (a & 7)])
                       * v_w2[a];
#pragma unroll
            for (int o = 16; o > 0; o >>= 1) pv += __shfl_xor(pv, o, 32);
            if (a == 0) {
                out[OUT_V + b] = pv + v_b2[0];
                pmag[b] = mg;
#pragma unroll
                for (int h = 0; h < 4; ++h) pent[(size_t)h * B_N + b] = entv[h];
            }
        }
#pragma unroll
        for (int i = 0; i < 8; ++i) cur[i] = nxt[i];
    }
}

// ---------------------------------------------------------------------------
// Deterministic final reduction
// ---------------------------------------------------------------------------
__global__ __launch_bounds__(256) void finalize_kernel(
        const float* __restrict__ pmag, const float* __restrict__ pent,
        float* __restrict__ out) {
    int which = blockIdx.x;   // 0..4
    const float* src = (which == 0) ? pmag : (pent + (size_t)(which - 1) * B_N);
    float s = 0.0f;
    for (int i = threadIdx.x; i < B_N; i += 256) s += src[i];
#pragma unroll
    for (int o = 32; o > 0; o >>= 1) s += __shfl_xor(s, o, 64);
    __shared__ float red[4];
    if ((threadIdx.x & 63) == 0) red[threadIdx.x >> 6] = s;
    __syncthreads();
    if (threadIdx.x == 0) {
        float tot = red[0] + red[1] + red[2] + red[3];
        if (which == 0) out[OUT_MAG] = 1e-3f * tot / (float)(B_N * A_N);
        else out[OUT_ENT + which - 1] = -tot / (float)B_N;
    }
}

// ---------------------------------------------------------------------------
extern "C" void kernel_launch(void* const* d_in, const int* in_sizes, int n_in,
                              void* d_out, int out_size, void* d_ws, size_t ws_size,
                              hipStream_t stream) {
    const float* states = (const float*)d_in[1];
    const float* sel_w1 = (const float*)d_in[2];
    const float* sel_b1 = (const float*)d_in[3];
    const float* sel_w2 = (const float*)d_in[4];
    const float* key_w  = (const float*)d_in[5];
    const float* v_w1   = (const float*)d_in[6];
    const float* v_b1   = (const float*)d_in[7];
    const float* v_w2   = (const float*)d_in[8];
    const float* v_b2   = (const float*)d_in[9];
    float* out = (float*)d_out;
    char* wsb  = (char*)d_ws;

    unsigned short* Wt  = (unsigned short*)(wsb + WS_WT);
    unsigned short* Mb  = (unsigned short*)(wsb + WS_MB);
    float* pmag         = (float*)(wsb + WS_PMAG);
    float* pent         = (float*)(wsb + WS_PENT);

    pack_w_kernel<<<dim3((NPADG * S_N + H_N * U_N * HYP_N + 255) / 256),
                    dim3(256), 0, stream>>>(sel_w1, v_w1, sel_w2, key_w, Wt, Mb);
    fused_kernel<<<dim3(B_N / FM_BM), dim3(256), 0, stream>>>(
        states, Wt, sel_b1, v_b1, Mb, v_w2, v_b2, out, pmag, pent);
    finalize_kernel<<<dim3(5), dim3(256), 0, stream>>>(pmag, pent, out);
}

// Round 8
// 279.295 us; speedup vs baseline: 1.1909x; 1.1909x over previous
//
#include <hip/hip_runtime.h>
#include <hip/hip_bf16.h>

// Problem constants
#define B_N 16384
#define A_N 32
#define U_N 64
#define S_N 2048
#define E_N 32
#define HYP_N 64
#define H_N 4
#define NREAL 288   // 256 selector-hypernet cols + 32 v-net cols
#define NPADG 320   // GEMM N padded to 320 (20 MFMA col-tiles)

// workspace byte offsets (16B-aligned)
#define WS_WT    0                         // Wt bf16 [320][2048] = 1310720 B
#define WS_MB    1310720                   // Mb bf16 [H][U][64]  = 32768 B
#define WS_PMAG  (WS_MB + 32768)
#define WS_PENT  (WS_PMAG + 65536)

// output layout (floats): head_attend [B,A] | v [B] | mag | ent [H]
#define OUT_V   (B_N * A_N)
#define OUT_MAG (OUT_V + B_N)
#define OUT_ENT (OUT_MAG + 1)

typedef __attribute__((ext_vector_type(8))) short bf16x8_t;
typedef __attribute__((ext_vector_type(4))) float floatx4_t;

#define AS1(p) ((const __attribute__((address_space(1))) void*)(p))
#define AS3(p) ((__attribute__((address_space(3))) void*)(p))

__device__ __forceinline__ unsigned short f2b(float f) {
    union { float f; unsigned u; } v; v.f = f;
    unsigned r = v.u + 0x7FFFu + ((v.u >> 16) & 1u);   // RNE
    return (unsigned short)(r >> 16);
}
__device__ __forceinline__ float b2f(unsigned x) {
    union { unsigned u; float f; } v; v.u = x << 16; return v.f;
}

// ---------------------------------------------------------------------------
// Pack: Wt bf16 [320][2048] (W^T of [sel_w1 | v_w1 | 0]) and
//       Mb bf16 [H][U][64]: M[h][u][k] = sum_e key_w[h][u][e]*sel_w2[h][k][e]
// ---------------------------------------------------------------------------
__global__ __launch_bounds__(256) void pack_w_kernel(
        const float* __restrict__ sel_w1, const float* __restrict__ v_w1,
        const float* __restrict__ sel_w2, const float* __restrict__ key_w,
        unsigned short* __restrict__ Wt, unsigned short* __restrict__ Mb) {
    int idx = blockIdx.x * 256 + threadIdx.x;
    if (idx < NPADG * S_N) {
        int n = idx >> 11;          // / 2048
        int k = idx & 2047;
        float val = 0.0f;
        if (n < 256) {
            int h = n >> 6, kk = n & 63;
            val = sel_w1[((size_t)h * S_N + k) * HYP_N + kk];
        } else if (n < NREAL) {
            val = v_w1[(size_t)k * E_N + (n - 256)];
        }
        Wt[idx] = f2b(val);
    } else if (idx < NPADG * S_N + H_N * U_N * HYP_N) {
        int j = idx - NPADG * S_N;          // [h][u][k]
        int h = j >> 12, u = (j >> 6) & 63, k = j & 63;
        const float* kw = key_w + ((size_t)h * U_N + u) * E_N;
        const float* w2 = sel_w2 + ((size_t)h * HYP_N + k) * E_N;
        float s = 0.0f;
#pragma unroll
        for (int e = 0; e < E_N; ++e) s = fmaf(kw[e], w2[e], s);
        Mb[j] = f2b(s);
    }
}

// ---------------------------------------------------------------------------
// Fused kernel v4 = r5 structure at 512 threads (8 waves, 2M x 4N split).
// BM=32, BN=320, BK=64, grid 512 -> 2 blocks/CU x 8 waves = 16 waves/CU
// (4 waves/SIMD — double r5's concurrency; that is the ONLY structural change
// to the K-loop). A fp32 read once from HBM, reg-prefetched one iter ahead
// by waves 0-3; B via global_load_lds w=16; XOR-swizzled LDS (validated ~0
// conflicts). Then bias/relu -> h1 LDS, phase T (MFMA t = h1 @ M^T, 8 waves =
// head x m-half), phase L (4 rows/wave).
// ---------------------------------------------------------------------------
#define FM_BM 32
#define FM_BK 64
#define NIT   (S_N / FM_BK)   // 32
#define H1_STRIDE 312   // shorts
#define TS_STRIDE 260   // floats

__global__ __launch_bounds__(512, 4) void fused_kernel(
        const float* __restrict__ states, const unsigned short* __restrict__ Wt,
        const float* __restrict__ sel_b1, const float* __restrict__ v_b1,
        const unsigned short* __restrict__ Mb,
        const float* __restrict__ v_w2, const float* __restrict__ v_b2,
        float* __restrict__ out, float* __restrict__ pmag, float* __restrict__ pent) {
    // pool: Asm 4096 | Bsm 40960 (tsb 33280 aliases) | h1b 19968 = 65024 B
    __shared__ __align__(16) char pool[4096 + 40960 + H1_STRIDE * FM_BM * 2];
    unsigned short* Asm = (unsigned short*)pool;
    unsigned short* Bsm = (unsigned short*)(pool + 4096);
    float*          tsb = (float*)(pool + 4096);                 // aliases Bsm
    unsigned short* h1b = (unsigned short*)(pool + 4096 + 40960);

    const int t = threadIdx.x;
    const int lane = t & 63;
    const int w = t >> 6;               // 0..7
    const int m0 = blockIdx.x * FM_BM;
    const int miw = (w & 1) * 16;       // 2-way M split: 16 rows/wave
    const int nw = (w >> 1) * 80;       // 4-way N split: 5 tiles/wave

    // A staging (threads 0..255 only): thread owns row ar = t>>3, k-octet acl
    const int ar = t >> 3, acl = t & 7;
    const float* ap = states + (size_t)(m0 + ar) * S_N + acl * 8;

    floatx4_t acc[5] = {};
    float4 a0, a1;

    // ---- prologue: A(0) regs -> LDS, B(0) glds, A(1) prefetch ----
    if (t < 256) {
        a0 = *(const float4*)(ap);
        a1 = *(const float4*)(ap + 4);
        int ph = acl ^ (ar & 7);
        uint4 o;
        o.x = (unsigned)f2b(a0.x) | ((unsigned)f2b(a0.y) << 16);
        o.y = (unsigned)f2b(a0.z) | ((unsigned)f2b(a0.w) << 16);
        o.z = (unsigned)f2b(a1.x) | ((unsigned)f2b(a1.y) << 16);
        o.w = (unsigned)f2b(a1.z) | ((unsigned)f2b(a1.w) << 16);
        *(uint4*)(Asm + (size_t)(ar * 8 + ph) * 8) = o;
    }
#pragma unroll
    for (int i = 0; i < 5; ++i) {
        int p = i * 512 + t, n = p >> 3, sl = p & 7;
        int cl = sl ^ (n & 7);
        __builtin_amdgcn_global_load_lds(AS1(Wt + (size_t)n * S_N + cl * 8),
                                         AS3(Bsm + p * 8), 16, 0, 0);
    }
    if (t < 256) {                      // A(1) prefetch
        a0 = *(const float4*)(ap + FM_BK);
        a1 = *(const float4*)(ap + FM_BK + 4);
    }
    __syncthreads();

    // ---- K-loop: 32 iters (r5 barrier structure) ----
    for (int it = 0; it < NIT; ++it) {
        // MFMA phase on current tile
#pragma unroll
        for (int s = 0; s < 2; ++s) {       // two K=32 steps
            const int c = s * 4 + (lane >> 4);
            int r = miw + (lane & 15);
            int pha = c ^ (r & 7);
            bf16x8_t afr = *(const bf16x8_t*)(Asm + r * 64 + pha * 8);
#pragma unroll
            for (int nt = 0; nt < 5; ++nt) {
                int n = nw + nt * 16 + (lane & 15);
                int ph = c ^ (n & 7);
                bf16x8_t bfr = *(const bf16x8_t*)(Bsm + n * 64 + ph * 8);
                acc[nt] = __builtin_amdgcn_mfma_f32_16x16x32_bf16(
                    afr, bfr, acc[nt], 0, 0, 0);
            }
        }
        __syncthreads();   // LDS readers done; A prefetch drained
        if (it < NIT - 1) {
            int k0 = (it + 1) * FM_BK;
            if (t < 256) {                  // A(it+1) regs -> LDS
                int ph = acl ^ (ar & 7);
                uint4 o;
                o.x = (unsigned)f2b(a0.x) | ((unsigned)f2b(a0.y) << 16);
                o.y = (unsigned)f2b(a0.z) | ((unsigned)f2b(a0.w) << 16);
                o.z = (unsigned)f2b(a1.x) | ((unsigned)f2b(a1.y) << 16);
                o.w = (unsigned)f2b(a1.z) | ((unsigned)f2b(a1.w) << 16);
                *(uint4*)(Asm + (size_t)(ar * 8 + ph) * 8) = o;
            }
#pragma unroll
            for (int i = 0; i < 5; ++i) {   // B(it+1)
                int p = i * 512 + t, n = p >> 3, sl = p & 7;
                int cl = sl ^ (n & 7);
                __builtin_amdgcn_global_load_lds(
                    AS1(Wt + (size_t)n * S_N + k0 + cl * 8),
                    AS3(Bsm + p * 8), 16, 0, 0);
            }
            if (it < NIT - 2 && t < 256) {  // A(it+2) prefetch
                const float* g = ap + (it + 2) * FM_BK;
                a0 = *(const float4*)(g);
                a1 = *(const float4*)(g + 4);
            }
            __syncthreads();   // staging visible before next MFMA phase
        }
    }

    // ---- bias + relu -> h1 LDS (bf16). C/D: col=lane&15, row=(lane>>4)*4+rg
    // layout per row: head h at h*72 (k 0..63), v-col j at (j>>3)*72+64+(j&7)
#pragma unroll
    for (int nt = 0; nt < 5; ++nt) {
        int n = nw + nt * 16 + (lane & 15);
        if (n >= NREAL) continue;
        float bias = (n < 256) ? sel_b1[n] : v_b1[n - 256];
        int slot = (n < 256) ? ((n >> 6) * 72 + (n & 63))
                             : (((n - 256) >> 3) * 72 + 64 + ((n - 256) & 7));
#pragma unroll
        for (int rg = 0; rg < 4; ++rg) {
            int r = miw + (lane >> 4) * 4 + rg;
            float v = acc[nt][rg] + bias;
            h1b[r * H1_STRIDE + slot] = f2b(v > 0.0f ? v : 0.0f);
        }
    }
    __syncthreads();   // h1 complete; all K-loop Bsm reads done -> tsb aliases

    // ---- phase T: wave w -> head h = w>>1, rows half = (w&1)*16; MFMA ----
    {
        const int h = w >> 1;
        const int rb = (w & 1) * 16;
        floatx4_t tacc[4] = {};
#pragma unroll
        for (int s = 0; s < 2; ++s) {
            int k0 = s * 32 + (lane >> 4) * 8;
            bf16x8_t afr = *(const bf16x8_t*)(h1b + (rb + (lane & 15)) * H1_STRIDE
                                              + h * 72 + k0);
#pragma unroll
            for (int ut = 0; ut < 4; ++ut) {
                int u = ut * 16 + (lane & 15);
                bf16x8_t bfr = *(const bf16x8_t*)(Mb + ((size_t)(h * U_N + u) * 64) + k0);
                tacc[ut] = __builtin_amdgcn_mfma_f32_16x16x32_bf16(
                    afr, bfr, tacc[ut], 0, 0, 0);
            }
        }
#pragma unroll
        for (int ut = 0; ut < 4; ++ut)
#pragma unroll
            for (int rg = 0; rg < 4; ++rg) {
                int r = rb + (lane >> 4) * 4 + rg;
                int u = ut * 16 + (lane & 15);
                tsb[r * TS_STRIDE + h * U_N + u] = tacc[ut][rg];
            }
    }
    __syncthreads();

    // ---- phase L: wave w handles rows w*4 .. w*4+3 ----
    const int a = lane & 31, uh = lane >> 5;
    float4 cur[8], nxt[8];
    {
        const float* up = states + (size_t)(m0 + w * 4) * S_N + a * 64 + uh * 32;
#pragma unroll
        for (int i = 0; i < 8; ++i) cur[i] = ((const float4*)up)[i];
    }
    for (int rr = 0; rr < 4; ++rr) {
        int r = w * 4 + rr;
        int b = m0 + r;
        if (rr < 3) {
            const float* up = states + (size_t)(b + 1) * S_N + a * 64 + uh * 32;
#pragma unroll
            for (int i = 0; i < 8; ++i) nxt[i] = ((const float4*)up)[i];
        }
        float pl[4];
#pragma unroll
        for (int h = 0; h < 4; ++h) {
            const float* tp = &tsb[r * TS_STRIDE + h * U_N + uh * 32];
            float s = 0.0f;
#pragma unroll
            for (int i = 0; i < 8; ++i) {
                float4 t4 = *(const float4*)(tp + i * 4);
                s = fmaf(cur[i].x, t4.x, s);
                s = fmaf(cur[i].y, t4.y, s);
                s = fmaf(cur[i].z, t4.z, s);
                s = fmaf(cur[i].w, t4.w, s);
            }
            pl[h] = s + __shfl_xor(s, 32, 64);   // combine u-halves
        }
        float mg = pl[0]*pl[0] + pl[1]*pl[1] + pl[2]*pl[2] + pl[3]*pl[3];
#pragma unroll
        for (int o = 16; o > 0; o >>= 1) mg += __shfl_xor(mg, o, 32);
        float hatt = 0.0f;
        float entv[4];
#pragma unroll
        for (int h = 0; h < 4; ++h) {
            float x = pl[h] * 0.17677669529663687f;   // 1/sqrt(E=32)
            float m = x;
#pragma unroll
            for (int o = 16; o > 0; o >>= 1) m = fmaxf(m, __shfl_xor(m, o, 32));
            float p = expf(x - m);
            float den = p;
#pragma unroll
            for (int o = 16; o > 0; o >>= 1) den += __shfl_xor(den, o, 32);
            float wv = p / den;
            hatt += wv;
            float e = wv * logf(wv + 1e-8f);
#pragma unroll
            for (int o = 16; o > 0; o >>= 1) e += __shfl_xor(e, o, 32);
            entv[h] = e;
        }
        if (uh == 0) {
            out[(size_t)b * A_N + a] = hatt;
            float pv = b2f((unsigned)h1b[r * H1_STRIDE + (a >> 3) * 72 + 64 + (a & 7)])
                       * v_w2[a];
#pragma unroll
            for (int o = 16; o > 0; o >>= 1) pv += __shfl_xor(pv, o, 32);
            if (a == 0) {
                out[OUT_V + b] = pv + v_b2[0];
                pmag[b] = mg;
#pragma unroll
                for (int h = 0; h < 4; ++h) pent[(size_t)h * B_N + b] = entv[h];
            }
        }
#pragma unroll
        for (int i = 0; i < 8; ++i) cur[i] = nxt[i];
    }
}

// ---------------------------------------------------------------------------
// Deterministic final reduction
// ---------------------------------------------------------------------------
__global__ __launch_bounds__(256) void finalize_kernel(
        const float* __restrict__ pmag, const float* __restrict__ pent,
        float* __restrict__ out) {
    int which = blockIdx.x;   // 0..4
    const float* src = (which == 0) ? pmag : (pent + (size_t)(which - 1) * B_N);
    float s = 0.0f;
    for (int i = threadIdx.x; i < B_N; i += 256) s += src[i];
#pragma unroll
    for (int o = 32; o > 0; o >>= 1) s += __shfl_xor(s, o, 64);
    __shared__ float red[4];
    if ((threadIdx.x & 63) == 0) red[threadIdx.x >> 6] = s;
    __syncthreads();
    if (threadIdx.x == 0) {
        float tot = red[0] + red[1] + red[2] + red[3];
        if (which == 0) out[OUT_MAG] = 1e-3f * tot / (float)(B_N * A_N);
        else out[OUT_ENT + which - 1] = -tot / (float)B_N;
    }
}

// ---------------------------------------------------------------------------
extern "C" void kernel_launch(void* const* d_in, const int* in_sizes, int n_in,
                              void* d_out, int out_size, void* d_ws, size_t ws_size,
                              hipStream_t stream) {
    const float* states = (const float*)d_in[1];
    const float* sel_w1 = (const float*)d_in[2];
    const float* sel_b1 = (const float*)d_in[3];
    const float* sel_w2 = (const float*)d_in[4];
    const float* key_w  = (const float*)d_in[5];
    const float* v_w1   = (const float*)d_in[6];
    const float* v_b1   = (const float*)d_in[7];
    const float* v_w2   = (const float*)d_in[8];
    const float* v_b2   = (const float*)d_in[9];
    float* out = (float*)d_out;
    char* wsb  = (char*)d_ws;

    unsigned short* Wt  = (unsigned short*)(wsb + WS_WT);
    unsigned short* Mb  = (unsigned short*)(wsb + WS_MB);
    float* pmag         = (float*)(wsb + WS_PMAG);
    float* pent         = (float*)(wsb + WS_PENT);

    pack_w_kernel<<<dim3((NPADG * S_N + H_N * U_N * HYP_N + 255) / 256),
                    dim3(256), 0, stream>>>(sel_w1, v_w1, sel_w2, key_w, Wt, Mb);
    fused_kernel<<<dim3(B_N / FM_BM), dim3(512), 0, stream>>>(
        states, Wt, sel_b1, v_b1, Mb, v_w2, v_b2, out, pmag, pent);
    finalize_kernel<<<dim3(5), dim3(256), 0, stream>>>(pmag, pent, out);
}